// Round 3
// baseline (1593.073 us; speedup 1.0000x reference)
//
#include <hip/hip_runtime.h>

#define N_NODES 50000
#define N_EDGES 1600000
#define IN_DIM 256
#define OUT_DIM 128
#define NEG_SLOPE 0.01f

#define NBUCK ((N_NODES + 63) / 64)      // 782 buckets of 64 rows
#define EPB   (N_EDGES / 256)            // 6250 edges per scatter block

// ---------------------------------------------------------------------------
// Kernel 1: h = x @ W   (fp32, LDS-tiled; no fp32 MFMA on CDNA4)
// ---------------------------------------------------------------------------
#define TM 64
#define TK 32

__global__ __launch_bounds__(256) void gemm_xw(const float* __restrict__ x,
                                               const float* __restrict__ w,
                                               float* __restrict__ h) {
    __shared__ float xs[TK][TM + 1];
    __shared__ float ws[TK][OUT_DIM + 4];

    const int tid  = threadIdx.x;
    const int row0 = blockIdx.x * TM;
    const int tx = tid & 15;
    const int ty = tid >> 4;

    float acc[4][8];
#pragma unroll
    for (int i = 0; i < 4; ++i)
#pragma unroll
        for (int j = 0; j < 8; ++j) acc[i][j] = 0.0f;

    const int loadRow = tid >> 2;
    const int loadK   = (tid & 3) * 8;
    const int wkr  = tid >> 5;
    const int wcol = (tid & 31) * 4;

    for (int kc = 0; kc < IN_DIM; kc += TK) {
        float4 xv0, xv1;
        const int gr = row0 + loadRow;
        if (gr < N_NODES) {
            const float4* xp = (const float4*)(x + (size_t)gr * IN_DIM + kc + loadK);
            xv0 = xp[0];
            xv1 = xp[1];
        } else {
            xv0 = make_float4(0.f, 0.f, 0.f, 0.f);
            xv1 = xv0;
        }
        xs[loadK + 0][loadRow] = xv0.x;
        xs[loadK + 1][loadRow] = xv0.y;
        xs[loadK + 2][loadRow] = xv0.z;
        xs[loadK + 3][loadRow] = xv0.w;
        xs[loadK + 4][loadRow] = xv1.x;
        xs[loadK + 5][loadRow] = xv1.y;
        xs[loadK + 6][loadRow] = xv1.z;
        xs[loadK + 7][loadRow] = xv1.w;

#pragma unroll
        for (int r = 0; r < 4; ++r) {
            const float4* wp = (const float4*)(w + (size_t)(kc + wkr + r * 8) * OUT_DIM + wcol);
            *(float4*)&ws[wkr + r * 8][wcol] = *wp;
        }
        __syncthreads();

#pragma unroll
        for (int k = 0; k < TK; ++k) {
            float xr[4];
            float wr[8];
#pragma unroll
            for (int i = 0; i < 4; ++i) xr[i] = xs[k][ty * 4 + i];
#pragma unroll
            for (int j = 0; j < 8; ++j) wr[j] = ws[k][tx * 8 + j];
#pragma unroll
            for (int i = 0; i < 4; ++i)
#pragma unroll
                for (int j = 0; j < 8; ++j) acc[i][j] += xr[i] * wr[j];
        }
        __syncthreads();
    }

#pragma unroll
    for (int i = 0; i < 4; ++i) {
        const int gr = row0 + ty * 4 + i;
        if (gr < N_NODES) {
            float* hp = h + (size_t)gr * OUT_DIM + tx * 8;
            ((float4*)hp)[0] = make_float4(acc[i][0], acc[i][1], acc[i][2], acc[i][3]);
            ((float4*)hp)[1] = make_float4(acc[i][4], acc[i][5], acc[i][6], acc[i][7]);
        }
    }
}

// ---------------------------------------------------------------------------
// Kernel 2: per-bucket histogram (LDS-staged, one global atomic per
// block-bucket; 256*782 = 200k global atomics total).
// ---------------------------------------------------------------------------
__global__ __launch_bounds__(256) void bucket_hist(const int* __restrict__ rows,
                                                   int* __restrict__ counts) {
    __shared__ int lhist[NBUCK];
    const int t = threadIdx.x;
    const int ebase = blockIdx.x * EPB;

    for (int b = t; b < NBUCK; b += 256) lhist[b] = 0;
    __syncthreads();

    for (int k = 0; k < EPB; k += 256) {
        if (k + t < EPB) atomicAdd(&lhist[rows[ebase + k + t] >> 6], 1);
    }
    __syncthreads();

    for (int b = t; b < NBUCK; b += 256) {
        const int c = lhist[b];
        if (c > 0) atomicAdd(&counts[b], c);
    }
}

// ---------------------------------------------------------------------------
// Kernel 3: exclusive scan of 782 bucket counts -> offsets[783] + cursor copy.
// ---------------------------------------------------------------------------
__global__ __launch_bounds__(1024) void scan_buckets(const int* __restrict__ counts,
                                                     int* __restrict__ offsets,
                                                     int* __restrict__ cursor) {
    __shared__ int s[1024];
    const int t = threadIdx.x;
    const int v = (t < NBUCK) ? counts[t] : 0;
    s[t] = v;
    __syncthreads();
    for (int off = 1; off < 1024; off <<= 1) {
        int u = (t >= off) ? s[t - off] : 0;
        __syncthreads();
        s[t] += u;
        __syncthreads();
    }
    if (t < NBUCK) {
        const int excl = s[t] - v;
        offsets[t] = excl;
        cursor[t]  = excl;
        if (t == NBUCK - 1) offsets[NBUCK] = s[t];
    }
}

// ---------------------------------------------------------------------------
// Kernel 4: bucket scatter. Each block: LDS hist of its 6250 edges ->
// reserve contiguous per-bucket ranges (1 atomic per block-bucket) ->
// write packed 8B records {col | (row&63)<<16, val} grouped by bucket.
// Runs of ~8 contiguous records per block-bucket -> coalescing-friendly.
// ---------------------------------------------------------------------------
__global__ __launch_bounds__(256) void bucket_scatter(const int* __restrict__ rows,
                                                      const int* __restrict__ cols,
                                                      const float* __restrict__ vals,
                                                      int* __restrict__ cursor,
                                                      int2* __restrict__ ebuf) {
    __shared__ int lcur[NBUCK];
    const int t = threadIdx.x;
    const int ebase = blockIdx.x * EPB;

    for (int b = t; b < NBUCK; b += 256) lcur[b] = 0;
    __syncthreads();

    for (int k = 0; k < EPB; k += 256) {
        if (k + t < EPB) atomicAdd(&lcur[rows[ebase + k + t] >> 6], 1);
    }
    __syncthreads();

    for (int b = t; b < NBUCK; b += 256) {
        const int c = lcur[b];
        lcur[b] = (c > 0) ? atomicAdd(&cursor[b], c) : 0;
    }
    __syncthreads();

    for (int k = 0; k < EPB; k += 256) {
        if (k + t < EPB) {
            const int e = ebase + k + t;
            const int r = rows[e];
            const int b = r >> 6;
            const int pos = atomicAdd(&lcur[b], 1);
            ebuf[pos] = make_int2(cols[e] | ((r & 63) << 16), __float_as_int(vals[e]));
        }
    }
}

// ---------------------------------------------------------------------------
// Kernel 5: bucket gather. One block per bucket; 64x128 fp32 tile in LDS.
// 4 waves on disjoint edge chunks; lane owns dims (lane, lane+64) -> LDS
// adds are 2-way bank aliased (free). Native ds_add_f32 LDS atomics resolve
// cross-wave same-row collisions. Fused leaky-ReLU; out written exactly once.
// ---------------------------------------------------------------------------
__global__ __launch_bounds__(256) void bucket_gather(const float* __restrict__ h,
                                                     const int* __restrict__ offsets,
                                                     const int2* __restrict__ ebuf,
                                                     float* __restrict__ out) {
    __shared__ float tile[64 * 128];
    const int t    = threadIdx.x;
    const int bkt  = blockIdx.x;
    const int wave = t >> 6;
    const int lane = t & 63;

    // zero tile
    float4* t4 = (float4*)tile;
    const float4 z4 = make_float4(0.f, 0.f, 0.f, 0.f);
#pragma unroll
    for (int i = 0; i < 8; ++i) t4[t + i * 256] = z4;
    __syncthreads();

    const int base = offsets[bkt];
    const int end  = offsets[bkt + 1];

    for (int e0 = base + wave * 64; e0 < end; e0 += 256) {
        const int n = min(64, end - e0);
        int2 rec = make_int2(0, 0);
        if (lane < n) rec = ebuf[e0 + lane];

        if (n == 64) {
#pragma unroll 8
            for (int j = 0; j < 64; ++j) {
                const int   p = __shfl(rec.x, j);
                const float v = __int_as_float(__shfl(rec.y, j));
                const int   c    = p & 0xFFFF;
                const int   rlow = p >> 16;
                const float* hc = h + (size_t)c * OUT_DIM;
                const float a0 = hc[lane];
                const float a1 = hc[lane + 64];
                atomicAdd(&tile[rlow * 128 + lane],      v * a0);
                atomicAdd(&tile[rlow * 128 + lane + 64], v * a1);
            }
        } else {
            for (int j = 0; j < n; ++j) {
                const int   p = __shfl(rec.x, j);
                const float v = __int_as_float(__shfl(rec.y, j));
                const int   c    = p & 0xFFFF;
                const int   rlow = p >> 16;
                const float* hc = h + (size_t)c * OUT_DIM;
                const float a0 = hc[lane];
                const float a1 = hc[lane + 64];
                atomicAdd(&tile[rlow * 128 + lane],      v * a0);
                atomicAdd(&tile[rlow * 128 + lane + 64], v * a1);
            }
        }
    }
    __syncthreads();

    // epilogue: leaky-ReLU + store (each out element written exactly once)
    const float4* ct4 = (const float4*)tile;
    float4* o4 = (float4*)out;
#pragma unroll
    for (int i = 0; i < 8; ++i) {
        const int idx = t + i * 256;            // float4 index within tile
        const int row = idx >> 5;               // 32 float4 per row
        if (bkt * 64 + row < N_NODES) {
            float4 v = ct4[idx];
            v.x = v.x >= 0.f ? v.x : NEG_SLOPE * v.x;
            v.y = v.y >= 0.f ? v.y : NEG_SLOPE * v.y;
            v.z = v.z >= 0.f ? v.z : NEG_SLOPE * v.z;
            v.w = v.w >= 0.f ? v.w : NEG_SLOPE * v.w;
            o4[(size_t)bkt * 2048 + idx] = v;
        }
    }
}

// ---------------------------------------------------------------------------
// Launch
// ---------------------------------------------------------------------------
extern "C" void kernel_launch(void* const* d_in, const int* in_sizes, int n_in,
                              void* d_out, int out_size, void* d_ws, size_t ws_size,
                              hipStream_t stream) {
    const float* x    = (const float*)d_in[0];
    const float* w    = (const float*)d_in[1];
    const float* vals = (const float*)d_in[2];
    const int*   rows = (const int*)d_in[3];
    const int*   cols = (const int*)d_in[4];
    float* out = (float*)d_out;

    char* ws = (char*)d_ws;
    size_t off = 0;
    auto alloc = [&](size_t bytes) {
        void* p = ws + off;
        off = (off + bytes + 255) & ~(size_t)255;
        return p;
    };
    float* h       = (float*)alloc((size_t)N_NODES * OUT_DIM * sizeof(float)); // 25.6 MB
    int2*  ebuf    = (int2*) alloc((size_t)N_EDGES * sizeof(int2));            // 12.8 MB
    int*   counts  = (int*)  alloc((size_t)NBUCK * sizeof(int));
    int*   offsets = (int*)  alloc((size_t)(NBUCK + 1) * sizeof(int));
    int*   cursor  = (int*)  alloc((size_t)NBUCK * sizeof(int));

    hipMemsetAsync(counts, 0, (size_t)NBUCK * sizeof(int), stream);

    const int gemm_blocks = (N_NODES + TM - 1) / TM;
    gemm_xw<<<gemm_blocks, 256, 0, stream>>>(x, w, h);

    bucket_hist<<<256, 256, 0, stream>>>(rows, counts);
    scan_buckets<<<1, 1024, 0, stream>>>(counts, offsets, cursor);
    bucket_scatter<<<256, 256, 0, stream>>>(rows, cols, vals, cursor, ebuf);
    bucket_gather<<<NBUCK, 256, 0, stream>>>(h, offsets, ebuf, out);
}

// Round 4
// 372.982 us; speedup vs baseline: 4.2712x; 4.2712x over previous
//
#include <hip/hip_runtime.h>

#define N_NODES 50000
#define N_EDGES 1600000
#define IN_DIM 256
#define OUT_DIM 128
#define NEG_SLOPE 0.01f

#define NBUCK ((N_NODES + 63) / 64)      // 782 buckets of 64 rows
#define EPB   (N_EDGES / 256)            // 6250 edges per scatter block
#define CAP   3072                       // max records per bucket (mean 2046, sd 45)

// ---------------------------------------------------------------------------
// Kernel 1: h = x @ W   (fp32, LDS-tiled; no fp32 MFMA on CDNA4)
// ---------------------------------------------------------------------------
#define TM 64
#define TK 32

__global__ __launch_bounds__(256) void gemm_xw(const float* __restrict__ x,
                                               const float* __restrict__ w,
                                               float* __restrict__ h) {
    __shared__ float xs[TK][TM + 1];
    __shared__ float ws[TK][OUT_DIM + 4];

    const int tid  = threadIdx.x;
    const int row0 = blockIdx.x * TM;
    const int tx = tid & 15;
    const int ty = tid >> 4;

    float acc[4][8];
#pragma unroll
    for (int i = 0; i < 4; ++i)
#pragma unroll
        for (int j = 0; j < 8; ++j) acc[i][j] = 0.0f;

    const int loadRow = tid >> 2;
    const int loadK   = (tid & 3) * 8;
    const int wkr  = tid >> 5;
    const int wcol = (tid & 31) * 4;

    for (int kc = 0; kc < IN_DIM; kc += TK) {
        float4 xv0, xv1;
        const int gr = row0 + loadRow;
        if (gr < N_NODES) {
            const float4* xp = (const float4*)(x + (size_t)gr * IN_DIM + kc + loadK);
            xv0 = xp[0];
            xv1 = xp[1];
        } else {
            xv0 = make_float4(0.f, 0.f, 0.f, 0.f);
            xv1 = xv0;
        }
        xs[loadK + 0][loadRow] = xv0.x;
        xs[loadK + 1][loadRow] = xv0.y;
        xs[loadK + 2][loadRow] = xv0.z;
        xs[loadK + 3][loadRow] = xv0.w;
        xs[loadK + 4][loadRow] = xv1.x;
        xs[loadK + 5][loadRow] = xv1.y;
        xs[loadK + 6][loadRow] = xv1.z;
        xs[loadK + 7][loadRow] = xv1.w;

#pragma unroll
        for (int r = 0; r < 4; ++r) {
            const float4* wp = (const float4*)(w + (size_t)(kc + wkr + r * 8) * OUT_DIM + wcol);
            *(float4*)&ws[wkr + r * 8][wcol] = *wp;
        }
        __syncthreads();

#pragma unroll
        for (int k = 0; k < TK; ++k) {
            float xr[4];
            float wr[8];
#pragma unroll
            for (int i = 0; i < 4; ++i) xr[i] = xs[k][ty * 4 + i];
#pragma unroll
            for (int j = 0; j < 8; ++j) wr[j] = ws[k][tx * 8 + j];
#pragma unroll
            for (int i = 0; i < 4; ++i)
#pragma unroll
                for (int j = 0; j < 8; ++j) acc[i][j] += xr[i] * wr[j];
        }
        __syncthreads();
    }

#pragma unroll
    for (int i = 0; i < 4; ++i) {
        const int gr = row0 + ty * 4 + i;
        if (gr < N_NODES) {
            float* hp = h + (size_t)gr * OUT_DIM + tx * 8;
            ((float4*)hp)[0] = make_float4(acc[i][0], acc[i][1], acc[i][2], acc[i][3]);
            ((float4*)hp)[1] = make_float4(acc[i][4], acc[i][5], acc[i][6], acc[i][7]);
        }
    }
}

// ---------------------------------------------------------------------------
// Kernel 2: per-bucket histogram (LDS-staged int atomics, one global atomic
// per block-bucket).
// ---------------------------------------------------------------------------
__global__ __launch_bounds__(256) void bucket_hist(const int* __restrict__ rows,
                                                   int* __restrict__ counts) {
    __shared__ int lhist[NBUCK];
    const int t = threadIdx.x;
    const int ebase = blockIdx.x * EPB;

    for (int b = t; b < NBUCK; b += 256) lhist[b] = 0;
    __syncthreads();

    for (int k = 0; k < EPB; k += 256) {
        if (k + t < EPB) atomicAdd(&lhist[rows[ebase + k + t] >> 6], 1);
    }
    __syncthreads();

    for (int b = t; b < NBUCK; b += 256) {
        const int c = lhist[b];
        if (c > 0) atomicAdd(&counts[b], c);
    }
}

// ---------------------------------------------------------------------------
// Kernel 3: exclusive scan of 782 bucket counts -> offsets[783] + cursor copy.
// ---------------------------------------------------------------------------
__global__ __launch_bounds__(1024) void scan_buckets(const int* __restrict__ counts,
                                                     int* __restrict__ offsets,
                                                     int* __restrict__ cursor) {
    __shared__ int s[1024];
    const int t = threadIdx.x;
    const int v = (t < NBUCK) ? counts[t] : 0;
    s[t] = v;
    __syncthreads();
    for (int off = 1; off < 1024; off <<= 1) {
        int u = (t >= off) ? s[t - off] : 0;
        __syncthreads();
        s[t] += u;
        __syncthreads();
    }
    if (t < NBUCK) {
        const int excl = s[t] - v;
        offsets[t] = excl;
        cursor[t]  = excl;
        if (t == NBUCK - 1) offsets[NBUCK] = s[t];
    }
}

// ---------------------------------------------------------------------------
// Kernel 4: bucket scatter. Per block: LDS hist of its 6250 edges -> reserve
// contiguous per-bucket ranges -> write packed 8B records
// { col | (row&63)<<16 , val } grouped by bucket.
// ---------------------------------------------------------------------------
__global__ __launch_bounds__(256) void bucket_scatter(const int* __restrict__ rows,
                                                      const int* __restrict__ cols,
                                                      const float* __restrict__ vals,
                                                      int* __restrict__ cursor,
                                                      int2* __restrict__ ebuf) {
    __shared__ int lcur[NBUCK];
    const int t = threadIdx.x;
    const int ebase = blockIdx.x * EPB;

    for (int b = t; b < NBUCK; b += 256) lcur[b] = 0;
    __syncthreads();

    for (int k = 0; k < EPB; k += 256) {
        if (k + t < EPB) atomicAdd(&lcur[rows[ebase + k + t] >> 6], 1);
    }
    __syncthreads();

    for (int b = t; b < NBUCK; b += 256) {
        const int c = lcur[b];
        lcur[b] = (c > 0) ? atomicAdd(&cursor[b], c) : 0;
    }
    __syncthreads();

    for (int k = 0; k < EPB; k += 256) {
        if (k + t < EPB) {
            const int e = ebase + k + t;
            const int r = rows[e];
            const int b = r >> 6;
            const int pos = atomicAdd(&lcur[b], 1);
            ebuf[pos] = make_int2(cols[e] | ((r & 63) << 16), __float_as_int(vals[e]));
        }
    }
}

// ---------------------------------------------------------------------------
// Kernel 5: bucket gather v2 — LDS counting-sort by row, then pure REGISTER
// accumulation (no fp atomics anywhere; round-3's LDS fp atomicAdd lowered
// to a ds_cmpxchg retry loop = 1393 us).
// One block per 64-row bucket. Wave w owns rows [16w,16w+16); lane owns
// output dims (2*lane, 2*lane+1). Records broadcast-read from LDS (same
// address across wave = free). Fused leaky-ReLU, out written exactly once.
// ---------------------------------------------------------------------------
__global__ __launch_bounds__(256) void bucket_gather(const float* __restrict__ h,
                                                     const int* __restrict__ offsets,
                                                     const int2* __restrict__ ebuf,
                                                     float* __restrict__ out) {
    __shared__ int2 stg[CAP];      // 24 KB staging (unsorted)
    __shared__ int2 srec[CAP];     // 24 KB sorted by row
    __shared__ int  hist[64];      // per-row count -> cursor
    __shared__ int  rowoff[65];

    const int t    = threadIdx.x;
    const int bkt  = blockIdx.x;
    const int wave = t >> 6;
    const int lane = t & 63;

    const int base = offsets[bkt];
    const int cnt  = offsets[bkt + 1] - base;

    if (t < 64) hist[t] = 0;
    __syncthreads();

    if (cnt <= CAP) {
        // ---- stage + per-row histogram ----
        for (int i = t; i < cnt; i += 256) {
            const int2 rec = ebuf[base + i];
            stg[i] = rec;
            atomicAdd(&hist[(rec.x >> 16) & 63], 1);
        }
        __syncthreads();

        // ---- exclusive scan over 64 rows (wave 0, shuffle scan) ----
        if (t < 64) {
            const int v = hist[t];
            int s = v;
#pragma unroll
            for (int off = 1; off < 64; off <<= 1) {
                const int u = __shfl_up(s, off);
                if (t >= off) s += u;
            }
            rowoff[t + 1] = s;
            hist[t] = s - v;            // exclusive prefix -> cursor
            if (t == 0) rowoff[0] = 0;
        }
        __syncthreads();

        // ---- counting sort into srec ----
        for (int i = t; i < cnt; i += 256) {
            const int2 rec = stg[i];
            const int pos = atomicAdd(&hist[(rec.x >> 16) & 63], 1);
            srec[pos] = rec;
        }
        __syncthreads();

        // ---- per-row register accumulation ----
        for (int rr = 0; rr < 16; ++rr) {
            const int row = wave * 16 + rr;
            const int beg = rowoff[row];
            const int end = rowoff[row + 1];
            float2 acc0 = make_float2(0.f, 0.f);
            float2 acc1 = make_float2(0.f, 0.f);

            int e = beg;
            for (; e + 4 <= end; e += 4) {
                const int2 r0 = srec[e + 0];
                const int2 r1 = srec[e + 1];
                const int2 r2 = srec[e + 2];
                const int2 r3 = srec[e + 3];
                const float2 m0 = ((const float2*)(h + (size_t)(r0.x & 0xFFFF) * OUT_DIM))[lane];
                const float2 m1 = ((const float2*)(h + (size_t)(r1.x & 0xFFFF) * OUT_DIM))[lane];
                const float2 m2 = ((const float2*)(h + (size_t)(r2.x & 0xFFFF) * OUT_DIM))[lane];
                const float2 m3 = ((const float2*)(h + (size_t)(r3.x & 0xFFFF) * OUT_DIM))[lane];
                const float v0 = __int_as_float(r0.y);
                const float v1 = __int_as_float(r1.y);
                const float v2 = __int_as_float(r2.y);
                const float v3 = __int_as_float(r3.y);
                acc0.x += v0 * m0.x; acc0.y += v0 * m0.y;
                acc1.x += v1 * m1.x; acc1.y += v1 * m1.y;
                acc0.x += v2 * m2.x; acc0.y += v2 * m2.y;
                acc1.x += v3 * m3.x; acc1.y += v3 * m3.y;
            }
            for (; e < end; ++e) {
                const int2 r0 = srec[e];
                const float2 m0 = ((const float2*)(h + (size_t)(r0.x & 0xFFFF) * OUT_DIM))[lane];
                const float v0 = __int_as_float(r0.y);
                acc0.x += v0 * m0.x; acc0.y += v0 * m0.y;
            }

            float2 acc = make_float2(acc0.x + acc1.x, acc0.y + acc1.y);
            const int grow = bkt * 64 + row;
            if (grow < N_NODES) {
                acc.x = acc.x >= 0.f ? acc.x : NEG_SLOPE * acc.x;
                acc.y = acc.y >= 0.f ? acc.y : NEG_SLOPE * acc.y;
                ((float2*)(out + (size_t)grow * OUT_DIM))[lane] = acc;
            }
        }
    } else {
        // ---- overflow fallback (statistically unreachable; correctness net) ----
        for (int rr = 0; rr < 16; ++rr) {
            const int row = wave * 16 + rr;
            float2 acc = make_float2(0.f, 0.f);
            for (int e = 0; e < cnt; ++e) {
                const int2 rec = ebuf[base + e];
                if (((rec.x >> 16) & 63) == row) {
                    const float2 m = ((const float2*)(h + (size_t)(rec.x & 0xFFFF) * OUT_DIM))[lane];
                    const float v = __int_as_float(rec.y);
                    acc.x += v * m.x; acc.y += v * m.y;
                }
            }
            const int grow = bkt * 64 + row;
            if (grow < N_NODES) {
                acc.x = acc.x >= 0.f ? acc.x : NEG_SLOPE * acc.x;
                acc.y = acc.y >= 0.f ? acc.y : NEG_SLOPE * acc.y;
                ((float2*)(out + (size_t)grow * OUT_DIM))[lane] = acc;
            }
        }
    }
}

// ---------------------------------------------------------------------------
// Launch
// ---------------------------------------------------------------------------
extern "C" void kernel_launch(void* const* d_in, const int* in_sizes, int n_in,
                              void* d_out, int out_size, void* d_ws, size_t ws_size,
                              hipStream_t stream) {
    const float* x    = (const float*)d_in[0];
    const float* w    = (const float*)d_in[1];
    const float* vals = (const float*)d_in[2];
    const int*   rows = (const int*)d_in[3];
    const int*   cols = (const int*)d_in[4];
    float* out = (float*)d_out;

    char* ws = (char*)d_ws;
    size_t off = 0;
    auto alloc = [&](size_t bytes) {
        void* p = ws + off;
        off = (off + bytes + 255) & ~(size_t)255;
        return p;
    };
    float* h       = (float*)alloc((size_t)N_NODES * OUT_DIM * sizeof(float)); // 25.6 MB
    int2*  ebuf    = (int2*) alloc((size_t)N_EDGES * sizeof(int2));            // 12.8 MB
    int*   counts  = (int*)  alloc((size_t)NBUCK * sizeof(int));
    int*   offsets = (int*)  alloc((size_t)(NBUCK + 1) * sizeof(int));
    int*   cursor  = (int*)  alloc((size_t)NBUCK * sizeof(int));

    hipMemsetAsync(counts, 0, (size_t)NBUCK * sizeof(int), stream);

    const int gemm_blocks = (N_NODES + TM - 1) / TM;
    gemm_xw<<<gemm_blocks, 256, 0, stream>>>(x, w, h);

    bucket_hist<<<256, 256, 0, stream>>>(rows, counts);
    scan_buckets<<<1, 1024, 0, stream>>>(counts, offsets, cursor);
    bucket_scatter<<<256, 256, 0, stream>>>(rows, cols, vals, cursor, ebuf);
    bucket_gather<<<NBUCK, 256, 0, stream>>>(h, offsets, ebuf, out);
}

// Round 5
// 322.300 us; speedup vs baseline: 4.9428x; 1.1573x over previous
//
#include <hip/hip_runtime.h>

#define N_NODES 50000
#define N_EDGES 1600000
#define IN_DIM 256
#define OUT_DIM 128
#define NEG_SLOPE 0.01f

#define NBUCK ((N_NODES + 63) / 64)      // 782 buckets of 64 rows
#define EPB   (N_EDGES / 256)            // 6250 edges per scatter block
#define CAP   3072                       // max records per bucket (mean 2046, sd 45)

// ---------------------------------------------------------------------------
// Kernel 1: h = x @ W   (fp32, LDS-tiled; no fp32 MFMA on CDNA4)
// ---------------------------------------------------------------------------
#define TM 64
#define TK 32

__global__ __launch_bounds__(256) void gemm_xw(const float* __restrict__ x,
                                               const float* __restrict__ w,
                                               float* __restrict__ h) {
    __shared__ float xs[TK][TM + 1];
    __shared__ float ws[TK][OUT_DIM + 4];

    const int tid  = threadIdx.x;
    const int row0 = blockIdx.x * TM;
    const int tx = tid & 15;
    const int ty = tid >> 4;

    float acc[4][8];
#pragma unroll
    for (int i = 0; i < 4; ++i)
#pragma unroll
        for (int j = 0; j < 8; ++j) acc[i][j] = 0.0f;

    const int loadRow = tid >> 2;
    const int loadK   = (tid & 3) * 8;
    const int wkr  = tid >> 5;
    const int wcol = (tid & 31) * 4;

    for (int kc = 0; kc < IN_DIM; kc += TK) {
        float4 xv0, xv1;
        const int gr = row0 + loadRow;
        if (gr < N_NODES) {
            const float4* xp = (const float4*)(x + (size_t)gr * IN_DIM + kc + loadK);
            xv0 = xp[0];
            xv1 = xp[1];
        } else {
            xv0 = make_float4(0.f, 0.f, 0.f, 0.f);
            xv1 = xv0;
        }
        xs[loadK + 0][loadRow] = xv0.x;
        xs[loadK + 1][loadRow] = xv0.y;
        xs[loadK + 2][loadRow] = xv0.z;
        xs[loadK + 3][loadRow] = xv0.w;
        xs[loadK + 4][loadRow] = xv1.x;
        xs[loadK + 5][loadRow] = xv1.y;
        xs[loadK + 6][loadRow] = xv1.z;
        xs[loadK + 7][loadRow] = xv1.w;

#pragma unroll
        for (int r = 0; r < 4; ++r) {
            const float4* wp = (const float4*)(w + (size_t)(kc + wkr + r * 8) * OUT_DIM + wcol);
            *(float4*)&ws[wkr + r * 8][wcol] = *wp;
        }
        __syncthreads();

#pragma unroll
        for (int k = 0; k < TK; ++k) {
            float xr[4];
            float wr[8];
#pragma unroll
            for (int i = 0; i < 4; ++i) xr[i] = xs[k][ty * 4 + i];
#pragma unroll
            for (int j = 0; j < 8; ++j) wr[j] = ws[k][tx * 8 + j];
#pragma unroll
            for (int i = 0; i < 4; ++i)
#pragma unroll
                for (int j = 0; j < 8; ++j) acc[i][j] += xr[i] * wr[j];
        }
        __syncthreads();
    }

#pragma unroll
    for (int i = 0; i < 4; ++i) {
        const int gr = row0 + ty * 4 + i;
        if (gr < N_NODES) {
            float* hp = h + (size_t)gr * OUT_DIM + tx * 8;
            ((float4*)hp)[0] = make_float4(acc[i][0], acc[i][1], acc[i][2], acc[i][3]);
            ((float4*)hp)[1] = make_float4(acc[i][4], acc[i][5], acc[i][6], acc[i][7]);
        }
    }
}

// ---------------------------------------------------------------------------
// Kernel 2: per-bucket histogram (LDS-staged int atomics, one global atomic
// per block-bucket).
// ---------------------------------------------------------------------------
__global__ __launch_bounds__(256) void bucket_hist(const int* __restrict__ rows,
                                                   int* __restrict__ counts) {
    __shared__ int lhist[NBUCK];
    const int t = threadIdx.x;
    const int ebase = blockIdx.x * EPB;

    for (int b = t; b < NBUCK; b += 256) lhist[b] = 0;
    __syncthreads();

    for (int k = 0; k < EPB; k += 256) {
        if (k + t < EPB) atomicAdd(&lhist[rows[ebase + k + t] >> 6], 1);
    }
    __syncthreads();

    for (int b = t; b < NBUCK; b += 256) {
        const int c = lhist[b];
        if (c > 0) atomicAdd(&counts[b], c);
    }
}

// ---------------------------------------------------------------------------
// Kernel 3: exclusive scan of 782 bucket counts -> offsets[783] + cursor copy.
// ---------------------------------------------------------------------------
__global__ __launch_bounds__(1024) void scan_buckets(const int* __restrict__ counts,
                                                     int* __restrict__ offsets,
                                                     int* __restrict__ cursor) {
    __shared__ int s[1024];
    const int t = threadIdx.x;
    const int v = (t < NBUCK) ? counts[t] : 0;
    s[t] = v;
    __syncthreads();
    for (int off = 1; off < 1024; off <<= 1) {
        int u = (t >= off) ? s[t - off] : 0;
        __syncthreads();
        s[t] += u;
        __syncthreads();
    }
    if (t < NBUCK) {
        const int excl = s[t] - v;
        offsets[t] = excl;
        cursor[t]  = excl;
        if (t == NBUCK - 1) offsets[NBUCK] = s[t];
    }
}

// ---------------------------------------------------------------------------
// Kernel 4: bucket scatter. Per block: LDS hist of its 6250 edges -> reserve
// contiguous per-bucket ranges -> write packed 8B records
// { col | (row&63)<<16 , val } grouped by bucket.
// ---------------------------------------------------------------------------
__global__ __launch_bounds__(256) void bucket_scatter(const int* __restrict__ rows,
                                                      const int* __restrict__ cols,
                                                      const float* __restrict__ vals,
                                                      int* __restrict__ cursor,
                                                      int2* __restrict__ ebuf) {
    __shared__ int lcur[NBUCK];
    const int t = threadIdx.x;
    const int ebase = blockIdx.x * EPB;

    for (int b = t; b < NBUCK; b += 256) lcur[b] = 0;
    __syncthreads();

    for (int k = 0; k < EPB; k += 256) {
        if (k + t < EPB) atomicAdd(&lcur[rows[ebase + k + t] >> 6], 1);
    }
    __syncthreads();

    for (int b = t; b < NBUCK; b += 256) {
        const int c = lcur[b];
        lcur[b] = (c > 0) ? atomicAdd(&cursor[b], c) : 0;
    }
    __syncthreads();

    for (int k = 0; k < EPB; k += 256) {
        if (k + t < EPB) {
            const int e = ebase + k + t;
            const int r = rows[e];
            const int b = r >> 6;
            const int pos = atomicAdd(&lcur[b], 1);
            ebuf[pos] = make_int2(cols[e] | ((r & 63) << 16), __float_as_int(vals[e]));
        }
    }
}

// ---------------------------------------------------------------------------
// Kernel 5: bucket gather v3 — counting sort straight from global ebuf into
// LDS srec (no staging copy; ebuf is read twice, streaming + L2-hot). LDS
// ~25 KB -> 6 blocks/CU (was 50 KB -> 3) to hide gather-load latency.
// Pure register accumulation, zero fp atomics. Fused leaky-ReLU.
// ---------------------------------------------------------------------------
__global__ __launch_bounds__(256) void bucket_gather(const float* __restrict__ h,
                                                     const int* __restrict__ offsets,
                                                     const int2* __restrict__ ebuf,
                                                     float* __restrict__ out) {
    __shared__ int2 srec[CAP];     // 24 KB sorted-by-row records
    __shared__ int  hist[64];      // per-row count -> cursor
    __shared__ int  rowoff[65];

    const int t    = threadIdx.x;
    const int bkt  = blockIdx.x;
    const int wave = t >> 6;
    const int lane = t & 63;

    const int base = offsets[bkt];
    const int cnt  = offsets[bkt + 1] - base;

    if (t < 64) hist[t] = 0;
    __syncthreads();

    if (cnt <= CAP) {
        // ---- pass 1: per-row histogram straight from global ----
        for (int i = t; i < cnt; i += 256) {
            const int rlow = (ebuf[base + i].x >> 16) & 63;
            atomicAdd(&hist[rlow], 1);
        }
        __syncthreads();

        // ---- exclusive scan over 64 rows (wave 0, shuffle scan) ----
        if (t < 64) {
            const int v = hist[t];
            int s = v;
#pragma unroll
            for (int off = 1; off < 64; off <<= 1) {
                const int u = __shfl_up(s, off);
                if (t >= off) s += u;
            }
            rowoff[t + 1] = s;
            hist[t] = s - v;            // exclusive prefix -> cursor
            if (t == 0) rowoff[0] = 0;
        }
        __syncthreads();

        // ---- pass 2: counting sort global -> LDS ----
        for (int i = t; i < cnt; i += 256) {
            const int2 rec = ebuf[base + i];
            const int pos = atomicAdd(&hist[(rec.x >> 16) & 63], 1);
            srec[pos] = rec;
        }
        __syncthreads();

        // ---- per-row register accumulation ----
        for (int rr = 0; rr < 16; ++rr) {
            const int row = wave * 16 + rr;
            const int beg = rowoff[row];
            const int end = rowoff[row + 1];
            float2 acc0 = make_float2(0.f, 0.f);
            float2 acc1 = make_float2(0.f, 0.f);

            int e = beg;
            for (; e + 4 <= end; e += 4) {
                const int2 r0 = srec[e + 0];
                const int2 r1 = srec[e + 1];
                const int2 r2 = srec[e + 2];
                const int2 r3 = srec[e + 3];
                const float2 m0 = ((const float2*)(h + (size_t)(r0.x & 0xFFFF) * OUT_DIM))[lane];
                const float2 m1 = ((const float2*)(h + (size_t)(r1.x & 0xFFFF) * OUT_DIM))[lane];
                const float2 m2 = ((const float2*)(h + (size_t)(r2.x & 0xFFFF) * OUT_DIM))[lane];
                const float2 m3 = ((const float2*)(h + (size_t)(r3.x & 0xFFFF) * OUT_DIM))[lane];
                const float v0 = __int_as_float(r0.y);
                const float v1 = __int_as_float(r1.y);
                const float v2 = __int_as_float(r2.y);
                const float v3 = __int_as_float(r3.y);
                acc0.x += v0 * m0.x; acc0.y += v0 * m0.y;
                acc1.x += v1 * m1.x; acc1.y += v1 * m1.y;
                acc0.x += v2 * m2.x; acc0.y += v2 * m2.y;
                acc1.x += v3 * m3.x; acc1.y += v3 * m3.y;
            }
            for (; e < end; ++e) {
                const int2 r0 = srec[e];
                const float2 m0 = ((const float2*)(h + (size_t)(r0.x & 0xFFFF) * OUT_DIM))[lane];
                const float v0 = __int_as_float(r0.y);
                acc0.x += v0 * m0.x; acc0.y += v0 * m0.y;
            }

            float2 acc = make_float2(acc0.x + acc1.x, acc0.y + acc1.y);
            const int grow = bkt * 64 + row;
            if (grow < N_NODES) {
                acc.x = acc.x >= 0.f ? acc.x : NEG_SLOPE * acc.x;
                acc.y = acc.y >= 0.f ? acc.y : NEG_SLOPE * acc.y;
                ((float2*)(out + (size_t)grow * OUT_DIM))[lane] = acc;
            }
        }
    } else {
        // ---- overflow fallback (statistically unreachable; correctness net) ----
        for (int rr = 0; rr < 16; ++rr) {
            const int row = wave * 16 + rr;
            float2 acc = make_float2(0.f, 0.f);
            for (int e = 0; e < cnt; ++e) {
                const int2 rec = ebuf[base + e];
                if (((rec.x >> 16) & 63) == row) {
                    const float2 m = ((const float2*)(h + (size_t)(rec.x & 0xFFFF) * OUT_DIM))[lane];
                    const float v = __int_as_float(rec.y);
                    acc.x += v * m.x; acc.y += v * m.y;
                }
            }
            const int grow = bkt * 64 + row;
            if (grow < N_NODES) {
                acc.x = acc.x >= 0.f ? acc.x : NEG_SLOPE * acc.x;
                acc.y = acc.y >= 0.f ? acc.y : NEG_SLOPE * acc.y;
                ((float2*)(out + (size_t)grow * OUT_DIM))[lane] = acc;
            }
        }
    }
}

// ---------------------------------------------------------------------------
// Launch
// ---------------------------------------------------------------------------
extern "C" void kernel_launch(void* const* d_in, const int* in_sizes, int n_in,
                              void* d_out, int out_size, void* d_ws, size_t ws_size,
                              hipStream_t stream) {
    const float* x    = (const float*)d_in[0];
    const float* w    = (const float*)d_in[1];
    const float* vals = (const float*)d_in[2];
    const int*   rows = (const int*)d_in[3];
    const int*   cols = (const int*)d_in[4];
    float* out = (float*)d_out;

    char* ws = (char*)d_ws;
    size_t off = 0;
    auto alloc = [&](size_t bytes) {
        void* p = ws + off;
        off = (off + bytes + 255) & ~(size_t)255;
        return p;
    };
    float* h       = (float*)alloc((size_t)N_NODES * OUT_DIM * sizeof(float)); // 25.6 MB
    int2*  ebuf    = (int2*) alloc((size_t)N_EDGES * sizeof(int2));            // 12.8 MB
    int*   counts  = (int*)  alloc((size_t)NBUCK * sizeof(int));
    int*   offsets = (int*)  alloc((size_t)(NBUCK + 1) * sizeof(int));
    int*   cursor  = (int*)  alloc((size_t)NBUCK * sizeof(int));

    hipMemsetAsync(counts, 0, (size_t)NBUCK * sizeof(int), stream);

    const int gemm_blocks = (N_NODES + TM - 1) / TM;
    gemm_xw<<<gemm_blocks, 256, 0, stream>>>(x, w, h);

    bucket_hist<<<256, 256, 0, stream>>>(rows, counts);
    scan_buckets<<<1, 1024, 0, stream>>>(counts, offsets, cursor);
    bucket_scatter<<<256, 256, 0, stream>>>(rows, cols, vals, cursor, ebuf);
    bucket_gather<<<NBUCK, 256, 0, stream>>>(h, offsets, ebuf, out);
}